// Round 13
// baseline (173.071 us; speedup 1.0000x reference)
//
#include <hip/hip_runtime.h>
#include <hip/hip_bf16.h>
#include <math.h>

#define BB 16
#define SS 2048
#define DD 512
#define MM 256
#define RR 64
#define KK 16
#define GPAD 68

__device__ __forceinline__ float wave_sum(float v) {
#pragma unroll
  for (int off = 32; off > 0; off >>= 1) v += __shfl_xor(v, off);
  return v;
}

__device__ __forceinline__ float sgnf(float v) {
  return (v > 0.f) ? 1.f : ((v < 0.f) ? -1.f : 0.f);
}

// ---------------------------------------------------------------------------
// LN(init_val) -> mv0 [M,D]; pt0[m,r] = (mv0[m]·rUt_w[:,r] + rUt_b[r])*r_w[r]*0.1
// ---------------------------------------------------------------------------
__global__ __launch_bounds__(256) void k_init(
    const float* __restrict__ init_val, const float* __restrict__ ln_g,
    const float* __restrict__ ln_b, const float* __restrict__ rUt_w,
    const float* __restrict__ rUt_b, const float* __restrict__ r_w,
    float* __restrict__ mv0, float* __restrict__ pt0) {
  int m = blockIdx.x, t = threadIdx.x;
  __shared__ float row[DD];
  __shared__ float red[8];
  float x0 = init_val[m * DD + t];
  float x1 = init_val[m * DD + t + 256];
  float s = wave_sum(x0 + x1);
  float sq = wave_sum(x0 * x0 + x1 * x1);
  if ((t & 63) == 0) { red[t >> 6] = s; red[4 + (t >> 6)] = sq; }
  __syncthreads();
  float mean = (red[0] + red[1] + red[2] + red[3]) * (1.0f / DD);
  float var = (red[4] + red[5] + red[6] + red[7]) * (1.0f / DD) - mean * mean;
  float rs = rsqrtf(var + 1e-5f);
  float n0 = (x0 - mean) * rs * ln_g[t] + ln_b[t];
  float n1 = (x1 - mean) * rs * ln_g[t + 256] + ln_b[t + 256];
  mv0[m * DD + t] = n0;
  mv0[m * DD + t + 256] = n1;
  row[t] = n0;
  row[t + 256] = n1;
  __syncthreads();
  if (t < RR) {
    float acc = rUt_b[t];
    for (int d = 0; d < DD; ++d) acc += row[d] * rUt_w[d * RR + t];
    pt0[m * RR + t] = acc * r_w[t] * 0.1f;
  }
}

// ---------------------------------------------------------------------------
// signed_softmax_state over 256 elements per block-row
// ---------------------------------------------------------------------------
__global__ __launch_bounds__(256) void k_state_softmax(
    const float* __restrict__ in, float* __restrict__ out) {
  int b = blockIdx.x, t = threadIdx.x;
  __shared__ float red[4];
  float v = in[b * MM + t];
  float a = fabsf(v);
  float mx = a;
#pragma unroll
  for (int off = 32; off > 0; off >>= 1) mx = fmaxf(mx, __shfl_xor(mx, off));
  if ((t & 63) == 0) red[t >> 6] = mx;
  __syncthreads();
  mx = fmaxf(fmaxf(red[0], red[1]), fmaxf(red[2], red[3]));
  __syncthreads();
  float e = expf(a - mx);
  float ssum = wave_sum(e);
  if ((t & 63) == 0) red[t >> 6] = ssum;
  __syncthreads();
  ssum = red[0] + red[1] + red[2] + red[3];
  out[b * MM + t] = sgnf(v) * e / ssum * 4.0f;
}

// ---------------------------------------------------------------------------
// k_ps v5: one WAVE per block, 4096 blocks -> 16 waves/CU (4/SIMD).
// Tile 32 rows x 64 cols, split-K x4 (128 k per block). W kept in REGISTERS
// (8-k chunk = 16 VGPR, L2-hot broadcast loads); A staged k-major in 1KB LDS:
// per k ONE conflict-free ds_read_b128 (banks rg*4) vs 32 FMA-insts.
// q==0 adds bias; consumer sums the 4 partials.
// ---------------------------------------------------------------------------
__global__ __launch_bounds__(64) void k_ps(
    const float* __restrict__ A, const float* __restrict__ W,
    const float* __restrict__ bias, float* __restrict__ C0,
    float* __restrict__ C1, float* __restrict__ C2, float* __restrict__ C3) {
  __shared__ float Ast[8][32];    // [k in chunk][row] 1KB
  int t = threadIdx.x;            // 0..63
  int rg = t >> 3;                // 0..7 -> rows rg*4..rg*4+3
  int cg = t & 7;                 // cols cg*8..cg*8+7
  int q = blockIdx.x >> 10;
  int rt = blockIdx.x & 1023;
  int row0 = rt * 32;
  int k0 = q * 128;
  float* C = (q == 0) ? C0 : (q == 1) ? C1 : (q == 2) ? C2 : C3;
  int lr = t >> 1;                // staging: row 0..31
  int ks = (t & 1) * 4;           // staging: k-offset 0 or 4
  float acc[4][8] = {};
  for (int ch = 0; ch < 16; ++ch) {
    int kc = k0 + ch * 8;
    // A slice for this chunk: 32 rows x 8 k (one float4 per thread)
    float4 av4 = *reinterpret_cast<const float4*>(
        &A[(size_t)(row0 + lr) * DD + kc + ks]);
    // W slice: 8 k x 8 cols into registers (broadcast across rg lanes)
    float4 wlo[8], whi[8];
#pragma unroll
    for (int j = 0; j < 8; ++j) {
      const float* wr = W + (size_t)(kc + j) * RR + cg * 8;
      wlo[j] = *reinterpret_cast<const float4*>(wr);
      whi[j] = *reinterpret_cast<const float4*>(wr + 4);
    }
    __syncthreads();   // previous chunk's reads complete before overwrite
    Ast[ks + 0][lr] = av4.x;
    Ast[ks + 1][lr] = av4.y;
    Ast[ks + 2][lr] = av4.z;
    Ast[ks + 3][lr] = av4.w;
    __syncthreads();
#pragma unroll
    for (int j = 0; j < 8; ++j) {
      float4 a4 = *reinterpret_cast<const float4*>(&Ast[j][rg * 4]);
      float wv[8] = {wlo[j].x, wlo[j].y, wlo[j].z, wlo[j].w,
                     whi[j].x, whi[j].y, whi[j].z, whi[j].w};
      float av[4] = {a4.x, a4.y, a4.z, a4.w};
#pragma unroll
      for (int i = 0; i < 4; ++i)
#pragma unroll
        for (int c = 0; c < 8; ++c) acc[i][c] += av[i] * wv[c];
    }
  }
  float bvx[8];
#pragma unroll
  for (int c = 0; c < 8; ++c) bvx[c] = (q == 0) ? bias[cg * 8 + c] : 0.f;
#pragma unroll
  for (int i = 0; i < 4; ++i) {
    int rr = row0 + rg * 4 + i;
    float4 o0, o1;
    o0.x = acc[i][0] + bvx[0]; o0.y = acc[i][1] + bvx[1];
    o0.z = acc[i][2] + bvx[2]; o0.w = acc[i][3] + bvx[3];
    o1.x = acc[i][4] + bvx[4]; o1.y = acc[i][5] + bvx[5];
    o1.z = acc[i][6] + bvx[6]; o1.w = acc[i][7] + bvx[7];
    *reinterpret_cast<float4*>(&C[(size_t)rr * RR + cg * 8]) = o0;
    *reinterpret_cast<float4*>(&C[(size_t)rr * RR + cg * 8 + 4]) = o1;
  }
}

// ---------------------------------------------------------------------------
// gemm_body (proven): 64-row tile, micro 4x4, K-chunk 32. Small pair GEMM.
// ---------------------------------------------------------------------------
template <bool TRANS_OUT>
__device__ __forceinline__ void gemm_body(
    const float* __restrict__ A, const float* __restrict__ W,
    const float* __restrict__ bias, const float* __restrict__ colscale,
    float csmul, const float* __restrict__ rowscale, float* __restrict__ C,
    int row0, float (*Ast)[GPAD], float (*Ws)[GPAD]) {
  int tid = threadIdx.x;
  int ty = tid >> 4, tx = tid & 15;
  float acc[4][4] = {};
  for (int kc = 0; kc < DD; kc += 32) {
#pragma unroll
    for (int i = 0; i < 2; ++i) {
      int s4 = i * 256 + tid;
      int r = s4 >> 3;
      int k4 = s4 & 7;
      float4 v = *reinterpret_cast<const float4*>(
          &A[(size_t)(row0 + r) * DD + kc + k4 * 4]);
      Ast[k4 * 4 + 0][r] = v.x;
      Ast[k4 * 4 + 1][r] = v.y;
      Ast[k4 * 4 + 2][r] = v.z;
      Ast[k4 * 4 + 3][r] = v.w;
    }
#pragma unroll
    for (int i = 0; i < 2; ++i) {
      int s4 = i * 256 + tid;
      int r = s4 >> 4;
      int c4 = s4 & 15;
      float4 v = *reinterpret_cast<const float4*>(
          &W[(size_t)(kc + r) * RR + c4 * 4]);
      *reinterpret_cast<float4*>(&Ws[r][c4 * 4]) = v;
    }
    __syncthreads();
#pragma unroll
    for (int k = 0; k < 32; ++k) {
      float4 a4 = *reinterpret_cast<const float4*>(&Ast[k][ty * 4]);
      float4 w4 = *reinterpret_cast<const float4*>(&Ws[k][tx * 4]);
      acc[0][0] += a4.x * w4.x; acc[0][1] += a4.x * w4.y;
      acc[0][2] += a4.x * w4.z; acc[0][3] += a4.x * w4.w;
      acc[1][0] += a4.y * w4.x; acc[1][1] += a4.y * w4.y;
      acc[1][2] += a4.y * w4.z; acc[1][3] += a4.y * w4.w;
      acc[2][0] += a4.z * w4.x; acc[2][1] += a4.z * w4.y;
      acc[2][2] += a4.z * w4.z; acc[2][3] += a4.z * w4.w;
      acc[3][0] += a4.w * w4.x; acc[3][1] += a4.w * w4.y;
      acc[3][2] += a4.w * w4.z; acc[3][3] += a4.w * w4.w;
    }
    __syncthreads();
  }
#pragma unroll
  for (int i = 0; i < 4; ++i) {
    int rr = row0 + ty * 4 + i;
    float rsc = rowscale ? rowscale[rr] : 1.f;
#pragma unroll
    for (int j = 0; j < 4; ++j) {
      int cc = tx * 4 + j;
      float v = acc[i][j] + bias[cc];
      if (colscale) v *= colscale[cc] * csmul;
      v *= rsc;
      if (TRANS_OUT) {
        C[((size_t)(rr >> 8) * RR + cc) * MM + (rr & 255)] = v;
      } else {
        C[(size_t)rr * RR + cc] = v;
      }
    }
  }
}

__global__ __launch_bounds__(256) void k_gemm_pair(
    const float* __restrict__ mv1, const float* __restrict__ pUt_w,
    const float* __restrict__ pUt_b, const float* __restrict__ p_w,
    const float* __restrict__ pUs_w, const float* __restrict__ pUs_b,
    const float* __restrict__ ms1, float* __restrict__ pt1,
    float* __restrict__ ps1T) {
  __shared__ float Ast[32][GPAD];
  __shared__ float Ws[32][GPAD];
  if (blockIdx.x < 64) {
    gemm_body<false>(mv1, pUt_w, pUt_b, p_w, 0.1f, nullptr, pt1,
                     blockIdx.x * 64, Ast, Ws);
  } else {
    gemm_body<true>(mv1, pUs_w, pUs_b, nullptr, 1.f, ms1, ps1T,
                    (blockIdx.x - 64) * 64, Ast, Ws);
  }
}

// ---------------------------------------------------------------------------
// k_scores: scores[b,m,j] = pt0[m,:]·(ps0+ps1+ps2+ps3)[b,j,:] (K=64).
// Tile 128m x 128j, 256 threads, micro 8m x 8j: per k 4 reads -> 64 FMA.
// ---------------------------------------------------------------------------
#define PSW 144
__device__ __forceinline__ int psw(int j) { return j + ((j >> 5) << 2); }

__global__ __launch_bounds__(256) void k_scores(
    const float* __restrict__ pt0, const float* __restrict__ ps0,
    const float* __restrict__ ps1, const float* __restrict__ ps2,
    const float* __restrict__ ps3, float* __restrict__ scores) {
  __shared__ float PtT[RR][128];  // [k][m] 32KB
  __shared__ float PsT[RR][PSW];  // [k][j skewed] 36KB
  int t = threadIdx.x;
  int b = blockIdx.z;
  int m0 = blockIdx.y * 128;
  int j0 = blockIdx.x * 128;
#pragma unroll
  for (int ii = 0; ii < 2; ++ii) {  // stage PtT: 2 4x4 tiles/thread
    int slot = ii * 256 + t;
    int tm4 = slot >> 4, tk4 = slot & 15;
    const float* base = pt0 + (size_t)(m0 + tm4 * 4) * RR + tk4 * 4;
    float4 v0 = *reinterpret_cast<const float4*>(base);
    float4 v1 = *reinterpret_cast<const float4*>(base + RR);
    float4 v2 = *reinterpret_cast<const float4*>(base + 2 * RR);
    float4 v3 = *reinterpret_cast<const float4*>(base + 3 * RR);
    float4 w;
    w.x = v0.x; w.y = v1.x; w.z = v2.x; w.w = v3.x;
    *reinterpret_cast<float4*>(&PtT[tk4 * 4 + 0][tm4 * 4]) = w;
    w.x = v0.y; w.y = v1.y; w.z = v2.y; w.w = v3.y;
    *reinterpret_cast<float4*>(&PtT[tk4 * 4 + 1][tm4 * 4]) = w;
    w.x = v0.z; w.y = v1.z; w.z = v2.z; w.w = v3.z;
    *reinterpret_cast<float4*>(&PtT[tk4 * 4 + 2][tm4 * 4]) = w;
    w.x = v0.w; w.y = v1.w; w.z = v2.w; w.w = v3.w;
    *reinterpret_cast<float4*>(&PtT[tk4 * 4 + 3][tm4 * 4]) = w;
  }
#pragma unroll
  for (int ii = 0; ii < 2; ++ii) {  // stage PsT: sum 4 partials
    int slot = ii * 256 + t;
    int jt = slot >> 4, kt = slot & 15;
    size_t off = ((size_t)b * SS + j0 + jt * 4) * RR + kt * 4;
    float4 v0, v1, v2, v3;
    {
      const float* p0 = ps0 + off;
      const float* p1 = ps1 + off;
      const float* p2 = ps2 + off;
      const float* p3 = ps3 + off;
#pragma unroll
      for (int rr2 = 0; rr2 < 4; ++rr2) {
        float4 a = *reinterpret_cast<const float4*>(p0 + rr2 * RR);
        float4 bq = *reinterpret_cast<const float4*>(p1 + rr2 * RR);
        float4 cq = *reinterpret_cast<const float4*>(p2 + rr2 * RR);
        float4 dq = *reinterpret_cast<const float4*>(p3 + rr2 * RR);
        float4 r;
        r.x = a.x + bq.x + cq.x + dq.x;
        r.y = a.y + bq.y + cq.y + dq.y;
        r.z = a.z + bq.z + cq.z + dq.z;
        r.w = a.w + bq.w + cq.w + dq.w;
        if (rr2 == 0) v0 = r; else if (rr2 == 1) v1 = r;
        else if (rr2 == 2) v2 = r; else v3 = r;
      }
    }
    int jc = psw(jt * 4);
    float4 w;
    w.x = v0.x; w.y = v1.x; w.z = v2.x; w.w = v3.x;
    *reinterpret_cast<float4*>(&PsT[kt * 4 + 0][jc]) = w;
    w.x = v0.y; w.y = v1.y; w.z = v2.y; w.w = v3.y;
    *reinterpret_cast<float4*>(&PsT[kt * 4 + 1][jc]) = w;
    w.x = v0.z; w.y = v1.z; w.z = v2.z; w.w = v3.z;
    *reinterpret_cast<float4*>(&PsT[kt * 4 + 2][jc]) = w;
    w.x = v0.w; w.y = v1.w; w.z = v2.w; w.w = v3.w;
    *reinterpret_cast<float4*>(&PsT[kt * 4 + 3][jc]) = w;
  }
  __syncthreads();
  int jg = t & 15;   // x8 j
  int mg = t >> 4;   // x8 m
  int jlo = psw(jg * 8);
  float acc[8][8] = {};
#pragma unroll
  for (int k = 0; k < RR; ++k) {
    float4 a0 = *reinterpret_cast<const float4*>(&PtT[k][mg * 8]);
    float4 a1 = *reinterpret_cast<const float4*>(&PtT[k][mg * 8 + 4]);
    float4 w0 = *reinterpret_cast<const float4*>(&PsT[k][jlo]);
    float4 w1 = *reinterpret_cast<const float4*>(&PsT[k][jlo + 4]);
    float av[8] = {a0.x, a0.y, a0.z, a0.w, a1.x, a1.y, a1.z, a1.w};
    float wv[8] = {w0.x, w0.y, w0.z, w0.w, w1.x, w1.y, w1.z, w1.w};
#pragma unroll
    for (int r = 0; r < 8; ++r)
#pragma unroll
      for (int cc = 0; cc < 8; ++cc) acc[r][cc] += av[r] * wv[cc];
  }
  float* obase =
      scores + (size_t)b * MM * SS + (size_t)(m0 + mg * 8) * SS + j0 + jg * 8;
#pragma unroll
  for (int r = 0; r < 8; ++r) {
    float4 o0, o1;
    o0.x = acc[r][0]; o0.y = acc[r][1]; o0.z = acc[r][2]; o0.w = acc[r][3];
    o1.x = acc[r][4]; o1.y = acc[r][5]; o1.z = acc[r][6]; o1.w = acc[r][7];
    *reinterpret_cast<float4*>(obase + (size_t)r * SS) = o0;
    *reinterpret_cast<float4*>(obase + (size_t)r * SS + 4) = o1;
  }
}

// ---------------------------------------------------------------------------
// One WAVE per (b,m) row. Scores kept in au[32] REGISTERS for the search;
// LDS copy only for value lookup at the end.
// ---------------------------------------------------------------------------
__global__ __launch_bounds__(256) void k_write(
    const float* __restrict__ scores, const float* __restrict__ token_val,
    const float* __restrict__ token_state, const float* __restrict__ mv0,
    const float* __restrict__ ms0, const float* __restrict__ ln_g,
    const float* __restrict__ ln_b, float* __restrict__ mv1,
    float* __restrict__ ms_w) {
  int t = threadIdx.x;
  int wave = t >> 6, lane = t & 63;
  int i = blockIdx.x;
  int slot = i >> 3;
  int b = 2 * (i & 7) + (slot >> 6);
  int m = (slot & 63) * 4 + wave;
  int row = b * MM + m;
  __shared__ float srl[4][SS];
  __shared__ int selj_sh[4][KK];
  float4* srl4 = reinterpret_cast<float4*>(&srl[wave][0]);
  const float* srow = scores + (size_t)row * SS;
  unsigned au[32];
  unsigned maxa = 0u;
#pragma unroll
  for (int ch = 0; ch < 8; ++ch) {
    float4 q = *reinterpret_cast<const float4*>(srow + (ch * 64 + lane) * 4);
    srl4[ch * 64 + lane] = q;
    au[ch * 4 + 0] = __float_as_uint(q.x) & 0x7fffffffu;
    au[ch * 4 + 1] = __float_as_uint(q.y) & 0x7fffffffu;
    au[ch * 4 + 2] = __float_as_uint(q.z) & 0x7fffffffu;
    au[ch * 4 + 3] = __float_as_uint(q.w) & 0x7fffffffu;
    maxa = max(maxa, max(max(au[ch * 4], au[ch * 4 + 1]),
                         max(au[ch * 4 + 2], au[ch * 4 + 3])));
  }
#pragma unroll
  for (int off = 32; off > 0; off >>= 1)
    maxa = max(maxa, (unsigned)__shfl_xor((int)maxa, off));
  unsigned lo = 0u, hi = maxa, thr = 0u;
  bool early = false;
  while (lo < hi) {
    unsigned mid = lo + ((hi - lo + 1u) >> 1);
    int cnt = 0;
#pragma unroll
    for (int c = 0; c < 32; ++c) cnt += __popcll(__ballot(au[c] >= mid));
    if (cnt == KK) { thr = mid; early = true; break; }
    if (cnt > KK) lo = mid; else hi = mid - 1u;
  }
  if (!early) thr = lo;
  unsigned long long ltmask = (1ull << lane) - 1ull;
  int s = 0;
  unsigned tiemask = 0u;
#pragma unroll
  for (int c = 0; c < 32; ++c) {
    bool sg = early ? (au[c] >= thr) : (au[c] > thr);
    unsigned long long mk = __ballot(sg);
    if (sg)
      selj_sh[wave][s + __popcll(mk & ltmask)] =
          (c >> 2) * 256 + lane * 4 + (c & 3);
    s += __popcll(mk);
    if (!early && au[c] == thr) tiemask |= 1u << c;
  }
  int taken = s;
  while (taken < KK) {
    int myj = 0x7fffffff;
#pragma unroll
    for (int c = 0; c < 32; ++c)
      if ((tiemask >> c) & 1u) {
        int j = (c >> 2) * 256 + lane * 4 + (c & 3);
        myj = min(myj, j);
      }
    int wj = myj;
#pragma unroll
    for (int off = 32; off > 0; off >>= 1) wj = min(wj, __shfl_xor(wj, off));
    if (wj == 0x7fffffff) break;
    if (((wj >> 2) & 63) == lane) tiemask &= ~(1u << (((wj >> 8) << 2) | (wj & 3)));
    if (lane == 0) selj_sh[wave][taken] = wj;
    ++taken;
  }
  int js[KK];
  float es[KK];
#pragma unroll
  for (int k = 0; k < KK; ++k) {
    js[k] = selj_sh[wave][k];
    es[k] = srl[wave][js[k]];
  }
  float mx = 0.f;
#pragma unroll
  for (int k = 0; k < KK; ++k) mx = fmaxf(mx, fabsf(es[k]));
  float ssum = 0.f;
#pragma unroll
  for (int k = 0; k < KK; ++k) {
    float ex = expf(fabsf(es[k]) - mx);
    ssum += ex;
    es[k] = sgnf(es[k]) * ex;
  }
  float inv = 1.f / ssum;
  int dbase = lane * 8;
  const float* m0row = mv0 + m * DD + dbase;
  float4 a0 = *reinterpret_cast<const float4*>(m0row);
  float4 a1 = *reinterpret_cast<const float4*>(m0row + 4);
  float acc[8] = {a0.x, a0.y, a0.z, a0.w, a1.x, a1.y, a1.z, a1.w};
  float stacc = 0.f;
#pragma unroll
  for (int k = 0; k < KK; ++k) {
    float e = es[k] * inv;
    const float* tv = token_val + ((size_t)b * SS + js[k]) * DD + dbase;
    float4 u0 = *reinterpret_cast<const float4*>(tv);
    float4 u1 = *reinterpret_cast<const float4*>(tv + 4);
    acc[0] += e * u0.x; acc[1] += e * u0.y; acc[2] += e * u0.z; acc[3] += e * u0.w;
    acc[4] += e * u1.x; acc[5] += e * u1.y; acc[6] += e * u1.z; acc[7] += e * u1.w;
    stacc += e * token_state[(size_t)b * SS + js[k]];
  }
  if (lane == 0) ms_w[row] = ms0[m] + stacc;
  float s1 = 0.f, s2 = 0.f;
#pragma unroll
  for (int c = 0; c < 8; ++c) { s1 += acc[c]; s2 += acc[c] * acc[c]; }
  s1 = wave_sum(s1);
  s2 = wave_sum(s2);
  float mean = s1 * (1.0f / DD);
  float var = s2 * (1.0f / DD) - mean * mean;
  float rs = rsqrtf(var + 1e-5f);
  float4 g0 = *reinterpret_cast<const float4*>(ln_g + dbase);
  float4 g1 = *reinterpret_cast<const float4*>(ln_g + dbase + 4);
  float4 b0v = *reinterpret_cast<const float4*>(ln_b + dbase);
  float4 b1v = *reinterpret_cast<const float4*>(ln_b + dbase + 4);
  float4 o0, o1;
  o0.x = (acc[0] - mean) * rs * g0.x + b0v.x;
  o0.y = (acc[1] - mean) * rs * g0.y + b0v.y;
  o0.z = (acc[2] - mean) * rs * g0.z + b0v.z;
  o0.w = (acc[3] - mean) * rs * g0.w + b0v.w;
  o1.x = (acc[4] - mean) * rs * g1.x + b1v.x;
  o1.y = (acc[5] - mean) * rs * g1.y + b1v.y;
  o1.z = (acc[6] - mean) * rs * g1.z + b1v.z;
  o1.w = (acc[7] - mean) * rs * g1.w + b1v.w;
  float* orow = mv1 + (size_t)row * DD + dbase;
  *reinterpret_cast<float4*>(orow) = o0;
  *reinterpret_cast<float4*>(orow + 4) = o1;
}

// ---------------------------------------------------------------------------
// One WAVE per (b,m): pscores[j] = pt1[row,:]·ps1T[b,:,j] (ms1 folded in);
// ballot-threshold top-16 -> edges -> gather mv1 -> residual -> LN -> out.
// ---------------------------------------------------------------------------
__global__ __launch_bounds__(256, 4) void k_prop(
    const float* __restrict__ pt1, const float* __restrict__ ps1T,
    const float* __restrict__ mv1, const float* __restrict__ ln_g,
    const float* __restrict__ ln_b, float* __restrict__ out) {
  int t = threadIdx.x;
  int wave = t >> 6, lane = t & 63;
  int row = blockIdx.x * 4 + wave;
  int b = row >> 8, m = row & 255;
  __shared__ int selj_sh[4][KK];
  __shared__ float selv_sh[4][KK];
  float ptval = pt1[(size_t)row * RR + lane];
  const float* pB = ps1T + (size_t)b * RR * MM + lane * 4;
  float sc[4] = {0.f, 0.f, 0.f, 0.f};
#pragma unroll 8
  for (int r = 0; r < RR; ++r) {
    float w = __shfl(ptval, r);
    float4 pv = *reinterpret_cast<const float4*>(pB + r * MM);
    sc[0] += w * pv.x; sc[1] += w * pv.y; sc[2] += w * pv.z; sc[3] += w * pv.w;
  }
  int jbase = lane * 4;
  unsigned au[4];
#pragma unroll
  for (int c = 0; c < 4; ++c) au[c] = __float_as_uint(sc[c]) & 0x7fffffffu;
  unsigned lo = 0u, hi = 0x7f800000u, thr = 0u;
  bool early = false;
  while (lo < hi) {
    unsigned mid = lo + ((hi - lo + 1u) >> 1);
    int cnt = 0;
#pragma unroll
    for (int c = 0; c < 4; ++c) cnt += __popcll(__ballot(au[c] >= mid));
    if (cnt == KK) { thr = mid; early = true; break; }
    if (cnt > KK) lo = mid; else hi = mid - 1u;
  }
  if (!early) thr = lo;
  unsigned long long ltmask = (1ull << lane) - 1ull;
  int s = 0;
  unsigned tiemask = 0u;
#pragma unroll
  for (int c = 0; c < 4; ++c) {
    bool sg = early ? (au[c] >= thr) : (au[c] > thr);
    unsigned long long mk = __ballot(sg);
    if (sg) {
      int slot = s + __popcll(mk & ltmask);
      selj_sh[wave][slot] = jbase + c;
      selv_sh[wave][slot] = sc[c];
    }
    s += __popcll(mk);
    if (!early && au[c] == thr) tiemask |= 1u << c;
  }
  int taken = s;
  while (taken < KK) {
    int myj = 0x7fffffff;
#pragma unroll
    for (int c = 0; c < 4; ++c)
      if ((tiemask >> c) & 1u) myj = min(myj, jbase + c);
    int wj = myj;
#pragma unroll
    for (int off = 32; off > 0; off >>= 1) wj = min(wj, __shfl_xor(wj, off));
    if (wj == 0x7fffffff) break;
    if (wj >= jbase && wj < jbase + 4) {
      tiemask &= ~(1u << (wj - jbase));
      selv_sh[wave][taken] = sc[wj - jbase];
      if (lane == (wj >> 2)) selj_sh[wave][taken] = wj;
    }
    ++taken;
  }
  int js[KK];
  float es[KK];
#pragma unroll
  for (int k = 0; k < KK; ++k) { js[k] = selj_sh[wave][k]; es[k] = selv_sh[wave][k]; }
  float mx = 0.f;
#pragma unroll
  for (int k = 0; k < KK; ++k) mx = fmaxf(mx, fabsf(es[k]));
  float ssum = 0.f;
#pragma unroll
  for (int k = 0; k < KK; ++k) {
    float ex = expf(fabsf(es[k]) - mx);
    ssum += ex;
    es[k] = sgnf(es[k]) * ex;
  }
  float inv = 1.f / ssum;
  int dbase = lane * 8;
  const float* mrow = mv1 + (size_t)row * DD + dbase;
  float4 a0 = *reinterpret_cast<const float4*>(mrow);
  float4 a1 = *reinterpret_cast<const float4*>(mrow + 4);
  float acc[8] = {a0.x, a0.y, a0.z, a0.w, a1.x, a1.y, a1.z, a1.w};
#pragma unroll
  for (int k = 0; k < KK; ++k) {
    float e = es[k] * inv;
    const float* pv = mv1 + ((size_t)b * MM + js[k]) * DD + dbase;
    float4 u0 = *reinterpret_cast<const float4*>(pv);
    float4 u1 = *reinterpret_cast<const float4*>(pv + 4);
    acc[0] += e * u0.x; acc[1] += e * u0.y; acc[2] += e * u0.z; acc[3] += e * u0.w;
    acc[4] += e * u1.x; acc[5] += e * u1.y; acc[6] += e * u1.z; acc[7] += e * u1.w;
  }
  float s1 = 0.f, s2 = 0.f;
#pragma unroll
  for (int c = 0; c < 8; ++c) { s1 += acc[c]; s2 += acc[c] * acc[c]; }
  s1 = wave_sum(s1);
  s2 = wave_sum(s2);
  float mean = s1 * (1.0f / DD);
  float var = s2 * (1.0f / DD) - mean * mean;
  float rs = rsqrtf(var + 1e-5f);
  float4 g0 = *reinterpret_cast<const float4*>(ln_g + dbase);
  float4 g1 = *reinterpret_cast<const float4*>(ln_g + dbase + 4);
  float4 b0v = *reinterpret_cast<const float4*>(ln_b + dbase);
  float4 b1v = *reinterpret_cast<const float4*>(ln_b + dbase + 4);
  float4 o0, o1;
  o0.x = (acc[0] - mean) * rs * g0.x + b0v.x;
  o0.y = (acc[1] - mean) * rs * g0.y + b0v.y;
  o0.z = (acc[2] - mean) * rs * g0.z + b0v.z;
  o0.w = (acc[3] - mean) * rs * g0.w + b0v.w;
  o1.x = (acc[4] - mean) * rs * g1.x + b1v.x;
  o1.y = (acc[5] - mean) * rs * g1.y + b1v.y;
  o1.z = (acc[6] - mean) * rs * g1.z + b1v.z;
  o1.w = (acc[7] - mean) * rs * g1.w + b1v.w;
  float* orow = out + (size_t)row * DD + dbase;
  *reinterpret_cast<float4*>(orow) = o0;
  *reinterpret_cast<float4*>(orow + 4) = o1;
}

extern "C" void kernel_launch(void* const* d_in, const int* in_sizes, int n_in,
                              void* d_out, int out_size, void* d_ws,
                              size_t ws_size, hipStream_t stream) {
  const float* token_val = (const float*)d_in[0];
  const float* token_state = (const float*)d_in[1];
  const float* init_state = (const float*)d_in[2];
  const float* init_val = (const float*)d_in[3];
  const float* rUs_w = (const float*)d_in[4];
  const float* rUs_b = (const float*)d_in[5];
  const float* rUt_w = (const float*)d_in[6];
  const float* rUt_b = (const float*)d_in[7];
  const float* r_w = (const float*)d_in[8];
  const float* pUs_w = (const float*)d_in[9];
  const float* pUs_b = (const float*)d_in[10];
  const float* pUt_w = (const float*)d_in[11];
  const float* pUt_b = (const float*)d_in[12];
  const float* p_w = (const float*)d_in[13];
  const float* ln_g = (const float*)d_in[14];
  const float* ln_b = (const float*)d_in[15];
  float* out = (float*)d_out;

  float* ws = (float*)d_ws;
  float* mv0 = ws;    ws += MM * DD;
  float* pt0 = ws;    ws += MM * RR;
  float* ms0 = ws;    ws += MM;
  float* ps = ws;     ws += (size_t)BB * SS * RR;    // ps quarter-0
  float* scores = ws; ws += (size_t)BB * MM * SS;
  float* mv1 = ws;    ws += (size_t)BB * MM * DD;    // aliases ps quarter-1
  float* ms_w = ws;   ws += BB * MM;
  float* ms1 = ws;    ws += BB * MM;
  float* pt1 = ws;    ws += (size_t)BB * MM * RR;
  float* ps1T = ws;   ws += (size_t)BB * RR * MM;
  float* ps2 = ws;    ws += (size_t)BB * SS * RR;    // ps quarter-2
  float* psB = mv1;   // quarter-1: consumed by k_scores before k_write
  float* psD = out;   // quarter-3: d_out as scratch, consumed by k_scores
                      // before k_prop writes the real output.

  k_init<<<MM, 256, 0, stream>>>(init_val, ln_g, ln_b, rUt_w, rUt_b, r_w, mv0, pt0);
  k_state_softmax<<<1, 256, 0, stream>>>(init_state, ms0);
  k_ps<<<4096, 64, 0, stream>>>(token_val, rUs_w, rUs_b, ps, psB, ps2, psD);
  dim3 gs(SS / 128, MM / 128, BB);
  k_scores<<<gs, 256, 0, stream>>>(pt0, ps, psB, ps2, psD, scores);
  k_write<<<(BB * MM) / 4, 256, 0, stream>>>(scores, token_val, token_state,
                                             mv0, ms0, ln_g, ln_b, mv1, ms_w);
  k_state_softmax<<<BB, 256, 0, stream>>>(ms_w, ms1);
  k_gemm_pair<<<128, 256, 0, stream>>>(mv1, pUt_w, pUt_b, p_w, pUs_w, pUs_b,
                                       ms1, pt1, ps1T);
  k_prop<<<(BB * MM) / 4, 256, 0, stream>>>(pt1, ps1T, mv1, ln_g, ln_b, out);
}

// Round 14
// 159.223 us; speedup vs baseline: 1.0870x; 1.0870x over previous
//
#include <hip/hip_runtime.h>
#include <hip/hip_bf16.h>
#include <math.h>

#define BB 16
#define SS 2048
#define DD 512
#define MM 256
#define RR 64
#define KK 16
#define GPAD 68

__device__ __forceinline__ float wave_sum(float v) {
#pragma unroll
  for (int off = 32; off > 0; off >>= 1) v += __shfl_xor(v, off);
  return v;
}

__device__ __forceinline__ float sgnf(float v) {
  return (v > 0.f) ? 1.f : ((v < 0.f) ? -1.f : 0.f);
}

// ---------------------------------------------------------------------------
// k_init: LN(init_val) -> mv0; pt0 = (mv0@rUt_w + b)*r_w*0.1.
// Block 0 additionally computes ms0 = signed_softmax_state(init_state).
// ---------------------------------------------------------------------------
__global__ __launch_bounds__(256) void k_init(
    const float* __restrict__ init_val, const float* __restrict__ init_state,
    const float* __restrict__ ln_g, const float* __restrict__ ln_b,
    const float* __restrict__ rUt_w, const float* __restrict__ rUt_b,
    const float* __restrict__ r_w, float* __restrict__ mv0,
    float* __restrict__ pt0, float* __restrict__ ms0) {
  int m = blockIdx.x, t = threadIdx.x;
  __shared__ float row[DD];
  __shared__ float red[8];
  __shared__ float red2[4];
  if (blockIdx.x == 0) {  // fused ms0 softmax (256 elements)
    float v = init_state[t];
    float a = fabsf(v);
    float mx = a;
#pragma unroll
    for (int off = 32; off > 0; off >>= 1) mx = fmaxf(mx, __shfl_xor(mx, off));
    if ((t & 63) == 0) red2[t >> 6] = mx;
    __syncthreads();
    mx = fmaxf(fmaxf(red2[0], red2[1]), fmaxf(red2[2], red2[3]));
    __syncthreads();
    float e = expf(a - mx);
    float ssum = wave_sum(e);
    if ((t & 63) == 0) red2[t >> 6] = ssum;
    __syncthreads();
    ssum = red2[0] + red2[1] + red2[2] + red2[3];
    ms0[t] = sgnf(v) * e / ssum * 4.0f;
    __syncthreads();
  }
  float x0 = init_val[m * DD + t];
  float x1 = init_val[m * DD + t + 256];
  float s = wave_sum(x0 + x1);
  float sq = wave_sum(x0 * x0 + x1 * x1);
  if ((t & 63) == 0) { red[t >> 6] = s; red[4 + (t >> 6)] = sq; }
  __syncthreads();
  float mean = (red[0] + red[1] + red[2] + red[3]) * (1.0f / DD);
  float var = (red[4] + red[5] + red[6] + red[7]) * (1.0f / DD) - mean * mean;
  float rs = rsqrtf(var + 1e-5f);
  float n0 = (x0 - mean) * rs * ln_g[t] + ln_b[t];
  float n1 = (x1 - mean) * rs * ln_g[t + 256] + ln_b[t + 256];
  mv0[m * DD + t] = n0;
  mv0[m * DD + t + 256] = n1;
  row[t] = n0;
  row[t + 256] = n1;
  __syncthreads();
  if (t < RR) {
    float acc = rUt_b[t];
    for (int d = 0; d < DD; ++d) acc += row[d] * rUt_w[d * RR + t];
    pt0[m * RR + t] = acc * r_w[t] * 0.1f;
  }
}

// ---------------------------------------------------------------------------
// signed_softmax_state over 256 elements per block-row (for ms1)
// ---------------------------------------------------------------------------
__global__ __launch_bounds__(256) void k_state_softmax(
    const float* __restrict__ in, float* __restrict__ out) {
  int b = blockIdx.x, t = threadIdx.x;
  __shared__ float red[4];
  float v = in[b * MM + t];
  float a = fabsf(v);
  float mx = a;
#pragma unroll
  for (int off = 32; off > 0; off >>= 1) mx = fmaxf(mx, __shfl_xor(mx, off));
  if ((t & 63) == 0) red[t >> 6] = mx;
  __syncthreads();
  mx = fmaxf(fmaxf(red[0], red[1]), fmaxf(red[2], red[3]));
  __syncthreads();
  float e = expf(a - mx);
  float ssum = wave_sum(e);
  if ((t & 63) == 0) red[t >> 6] = ssum;
  __syncthreads();
  ssum = red[0] + red[1] + red[2] + red[3];
  out[b * MM + t] = sgnf(v) * e / ssum * 4.0f;
}

// ---------------------------------------------------------------------------
// gemm_body (R6, best measured k_ps variant): 64-row tile, micro 4x4,
// K-chunk 32. A staged transposed Ast[k][row] pad 68; W staged Ws[k][col].
// ---------------------------------------------------------------------------
template <bool TRANS_OUT>
__device__ __forceinline__ void gemm_body(
    const float* __restrict__ A, const float* __restrict__ W,
    const float* __restrict__ bias, const float* __restrict__ colscale,
    float csmul, const float* __restrict__ rowscale, float* __restrict__ C,
    int row0, float (*Ast)[GPAD], float (*Ws)[GPAD]) {
  int tid = threadIdx.x;
  int ty = tid >> 4, tx = tid & 15;
  float acc[4][4] = {};
  for (int kc = 0; kc < DD; kc += 32) {
#pragma unroll
    for (int i = 0; i < 2; ++i) {
      int s4 = i * 256 + tid;
      int r = s4 >> 3;
      int k4 = s4 & 7;
      float4 v = *reinterpret_cast<const float4*>(
          &A[(size_t)(row0 + r) * DD + kc + k4 * 4]);
      Ast[k4 * 4 + 0][r] = v.x;
      Ast[k4 * 4 + 1][r] = v.y;
      Ast[k4 * 4 + 2][r] = v.z;
      Ast[k4 * 4 + 3][r] = v.w;
    }
#pragma unroll
    for (int i = 0; i < 2; ++i) {
      int s4 = i * 256 + tid;
      int r = s4 >> 4;
      int c4 = s4 & 15;
      float4 v = *reinterpret_cast<const float4*>(
          &W[(size_t)(kc + r) * RR + c4 * 4]);
      *reinterpret_cast<float4*>(&Ws[r][c4 * 4]) = v;
    }
    __syncthreads();
#pragma unroll
    for (int k = 0; k < 32; ++k) {
      float4 a4 = *reinterpret_cast<const float4*>(&Ast[k][ty * 4]);
      float4 w4 = *reinterpret_cast<const float4*>(&Ws[k][tx * 4]);
      acc[0][0] += a4.x * w4.x; acc[0][1] += a4.x * w4.y;
      acc[0][2] += a4.x * w4.z; acc[0][3] += a4.x * w4.w;
      acc[1][0] += a4.y * w4.x; acc[1][1] += a4.y * w4.y;
      acc[1][2] += a4.y * w4.z; acc[1][3] += a4.y * w4.w;
      acc[2][0] += a4.z * w4.x; acc[2][1] += a4.z * w4.y;
      acc[2][2] += a4.z * w4.z; acc[2][3] += a4.z * w4.w;
      acc[3][0] += a4.w * w4.x; acc[3][1] += a4.w * w4.y;
      acc[3][2] += a4.w * w4.z; acc[3][3] += a4.w * w4.w;
    }
    __syncthreads();
  }
#pragma unroll
  for (int i = 0; i < 4; ++i) {
    int rr = row0 + ty * 4 + i;
    float rsc = rowscale ? rowscale[rr] : 1.f;
    if (TRANS_OUT) {
#pragma unroll
      for (int j = 0; j < 4; ++j) {
        int cc = tx * 4 + j;
        float v = acc[i][j] + bias[cc];
        if (colscale) v *= colscale[cc] * csmul;
        v *= rsc;
        C[((size_t)(rr >> 8) * RR + cc) * MM + (rr & 255)] = v;
      }
    } else {
      float4 o;
      o.x = acc[i][0] + bias[tx * 4];
      o.y = acc[i][1] + bias[tx * 4 + 1];
      o.z = acc[i][2] + bias[tx * 4 + 2];
      o.w = acc[i][3] + bias[tx * 4 + 3];
      if (colscale) {
        o.x *= colscale[tx * 4] * csmul; o.y *= colscale[tx * 4 + 1] * csmul;
        o.z *= colscale[tx * 4 + 2] * csmul; o.w *= colscale[tx * 4 + 3] * csmul;
      }
      o.x *= rsc; o.y *= rsc; o.z *= rsc; o.w *= rsc;
      *reinterpret_cast<float4*>(&C[(size_t)rr * RR + tx * 4]) = o;
    }
  }
}

__global__ __launch_bounds__(256) void k_ps(
    const float* __restrict__ A, const float* __restrict__ W,
    const float* __restrict__ bias, float* __restrict__ C) {
  __shared__ float Ast[32][GPAD];
  __shared__ float Ws[32][GPAD];
  gemm_body<false>(A, W, bias, nullptr, 1.f, nullptr, C, blockIdx.x * 64,
                   Ast, Ws);
}

__global__ __launch_bounds__(256) void k_gemm_pair(
    const float* __restrict__ mv1, const float* __restrict__ pUt_w,
    const float* __restrict__ pUt_b, const float* __restrict__ p_w,
    const float* __restrict__ pUs_w, const float* __restrict__ pUs_b,
    const float* __restrict__ ms1, float* __restrict__ pt1,
    float* __restrict__ ps1T) {
  __shared__ float Ast[32][GPAD];
  __shared__ float Ws[32][GPAD];
  if (blockIdx.x < 64) {
    gemm_body<false>(mv1, pUt_w, pUt_b, p_w, 0.1f, nullptr, pt1,
                     blockIdx.x * 64, Ast, Ws);
  } else {
    gemm_body<true>(mv1, pUs_w, pUs_b, nullptr, 1.f, ms1, ps1T,
                    (blockIdx.x - 64) * 64, Ast, Ws);
  }
}

// ---------------------------------------------------------------------------
// k_scores: scores[b,m,j] = pt0[m,:]·ps[b,j,:] (K=64).
// Tile 128m x 128j, 256 threads, micro 8m x 8j: per k 4 reads -> 64 FMA.
// ---------------------------------------------------------------------------
#define PSW 144
__device__ __forceinline__ int psw(int j) { return j + ((j >> 5) << 2); }

__global__ __launch_bounds__(256) void k_scores(
    const float* __restrict__ pt0, const float* __restrict__ ps,
    float* __restrict__ scores) {
  __shared__ float PtT[RR][128];  // [k][m] 32KB
  __shared__ float PsT[RR][PSW];  // [k][j skewed] 36KB
  int t = threadIdx.x;
  int b = blockIdx.z;
  int m0 = blockIdx.y * 128;
  int j0 = blockIdx.x * 128;
#pragma unroll
  for (int ii = 0; ii < 2; ++ii) {  // stage PtT: 2 4x4 tiles/thread
    int slot = ii * 256 + t;
    int tm4 = slot >> 4, tk4 = slot & 15;
    const float* base = pt0 + (size_t)(m0 + tm4 * 4) * RR + tk4 * 4;
    float4 v0 = *reinterpret_cast<const float4*>(base);
    float4 v1 = *reinterpret_cast<const float4*>(base + RR);
    float4 v2 = *reinterpret_cast<const float4*>(base + 2 * RR);
    float4 v3 = *reinterpret_cast<const float4*>(base + 3 * RR);
    float4 w;
    w.x = v0.x; w.y = v1.x; w.z = v2.x; w.w = v3.x;
    *reinterpret_cast<float4*>(&PtT[tk4 * 4 + 0][tm4 * 4]) = w;
    w.x = v0.y; w.y = v1.y; w.z = v2.y; w.w = v3.y;
    *reinterpret_cast<float4*>(&PtT[tk4 * 4 + 1][tm4 * 4]) = w;
    w.x = v0.z; w.y = v1.z; w.z = v2.z; w.w = v3.z;
    *reinterpret_cast<float4*>(&PtT[tk4 * 4 + 2][tm4 * 4]) = w;
    w.x = v0.w; w.y = v1.w; w.z = v2.w; w.w = v3.w;
    *reinterpret_cast<float4*>(&PtT[tk4 * 4 + 3][tm4 * 4]) = w;
  }
#pragma unroll
  for (int ii = 0; ii < 2; ++ii) {  // stage PsT: 2 4x4 tiles/thread
    int slot = ii * 256 + t;
    int jt = slot >> 4, kt = slot & 15;
    const float* base = ps + ((size_t)b * SS + j0 + jt * 4) * RR + kt * 4;
    float4 v0 = *reinterpret_cast<const float4*>(base);
    float4 v1 = *reinterpret_cast<const float4*>(base + RR);
    float4 v2 = *reinterpret_cast<const float4*>(base + 2 * RR);
    float4 v3 = *reinterpret_cast<const float4*>(base + 3 * RR);
    int jc = psw(jt * 4);
    float4 w;
    w.x = v0.x; w.y = v1.x; w.z = v2.x; w.w = v3.x;
    *reinterpret_cast<float4*>(&PsT[kt * 4 + 0][jc]) = w;
    w.x = v0.y; w.y = v1.y; w.z = v2.y; w.w = v3.y;
    *reinterpret_cast<float4*>(&PsT[kt * 4 + 1][jc]) = w;
    w.x = v0.z; w.y = v1.z; w.z = v2.z; w.w = v3.z;
    *reinterpret_cast<float4*>(&PsT[kt * 4 + 2][jc]) = w;
    w.x = v0.w; w.y = v1.w; w.z = v2.w; w.w = v3.w;
    *reinterpret_cast<float4*>(&PsT[kt * 4 + 3][jc]) = w;
  }
  __syncthreads();
  int jg = t & 15;   // x8 j
  int mg = t >> 4;   // x8 m
  int jlo = psw(jg * 8);
  float acc[8][8] = {};
#pragma unroll
  for (int k = 0; k < RR; ++k) {
    float4 a0 = *reinterpret_cast<const float4*>(&PtT[k][mg * 8]);
    float4 a1 = *reinterpret_cast<const float4*>(&PtT[k][mg * 8 + 4]);
    float4 w0 = *reinterpret_cast<const float4*>(&PsT[k][jlo]);
    float4 w1 = *reinterpret_cast<const float4*>(&PsT[k][jlo + 4]);
    float av[8] = {a0.x, a0.y, a0.z, a0.w, a1.x, a1.y, a1.z, a1.w};
    float wv[8] = {w0.x, w0.y, w0.z, w0.w, w1.x, w1.y, w1.z, w1.w};
#pragma unroll
    for (int r = 0; r < 8; ++r)
#pragma unroll
      for (int cc = 0; cc < 8; ++cc) acc[r][cc] += av[r] * wv[cc];
  }
  float* obase =
      scores + (size_t)b * MM * SS + (size_t)(m0 + mg * 8) * SS + j0 + jg * 8;
#pragma unroll
  for (int r = 0; r < 8; ++r) {
    float4 o0, o1;
    o0.x = acc[r][0]; o0.y = acc[r][1]; o0.z = acc[r][2]; o0.w = acc[r][3];
    o1.x = acc[r][4]; o1.y = acc[r][5]; o1.z = acc[r][6]; o1.w = acc[r][7];
    *reinterpret_cast<float4*>(obase + (size_t)r * SS) = o0;
    *reinterpret_cast<float4*>(obase + (size_t)r * SS + 4) = o1;
  }
}

// ---------------------------------------------------------------------------
// One WAVE per (b,m) row. Scores held in au[32] registers for the ballot
// binary search; selected values re-read from L2-hot scores row (no LDS
// staging). XCD b-affinity swizzle.
// ---------------------------------------------------------------------------
__global__ __launch_bounds__(256) void k_write(
    const float* __restrict__ scores, const float* __restrict__ token_val,
    const float* __restrict__ token_state, const float* __restrict__ mv0,
    const float* __restrict__ ms0, const float* __restrict__ ln_g,
    const float* __restrict__ ln_b, float* __restrict__ mv1,
    float* __restrict__ ms_w) {
  int t = threadIdx.x;
  int wave = t >> 6, lane = t & 63;
  int i = blockIdx.x;
  int slot = i >> 3;
  int b = 2 * (i & 7) + (slot >> 6);
  int m = (slot & 63) * 4 + wave;
  int row = b * MM + m;
  __shared__ int selj_sh[4][KK];
  const float* srow = scores + (size_t)row * SS;
  unsigned au[32];
  unsigned maxa = 0u;
#pragma unroll
  for (int ch = 0; ch < 8; ++ch) {
    float4 q = *reinterpret_cast<const float4*>(srow + (ch * 64 + lane) * 4);
    au[ch * 4 + 0] = __float_as_uint(q.x) & 0x7fffffffu;
    au[ch * 4 + 1] = __float_as_uint(q.y) & 0x7fffffffu;
    au[ch * 4 + 2] = __float_as_uint(q.z) & 0x7fffffffu;
    au[ch * 4 + 3] = __float_as_uint(q.w) & 0x7fffffffu;
    maxa = max(maxa, max(max(au[ch * 4], au[ch * 4 + 1]),
                         max(au[ch * 4 + 2], au[ch * 4 + 3])));
  }
#pragma unroll
  for (int off = 32; off > 0; off >>= 1)
    maxa = max(maxa, (unsigned)__shfl_xor((int)maxa, off));
  unsigned lo = 0u, hi = maxa, thr = 0u;
  bool early = false;
  while (lo < hi) {
    unsigned mid = lo + ((hi - lo + 1u) >> 1);
    int cnt = 0;
#pragma unroll
    for (int c = 0; c < 32; ++c) cnt += __popcll(__ballot(au[c] >= mid));
    if (cnt == KK) { thr = mid; early = true; break; }
    if (cnt > KK) lo = mid; else hi = mid - 1u;
  }
  if (!early) thr = lo;
  unsigned long long ltmask = (1ull << lane) - 1ull;
  int s = 0;
  unsigned tiemask = 0u;
#pragma unroll
  for (int c = 0; c < 32; ++c) {
    bool sg = early ? (au[c] >= thr) : (au[c] > thr);
    unsigned long long mk = __ballot(sg);
    if (sg)
      selj_sh[wave][s + __popcll(mk & ltmask)] =
          (c >> 2) * 256 + lane * 4 + (c & 3);
    s += __popcll(mk);
    if (!early && au[c] == thr) tiemask |= 1u << c;
  }
  int taken = s;
  while (taken < KK) {
    int myj = 0x7fffffff;
#pragma unroll
    for (int c = 0; c < 32; ++c)
      if ((tiemask >> c) & 1u) {
        int j = (c >> 2) * 256 + lane * 4 + (c & 3);
        myj = min(myj, j);
      }
    int wj = myj;
#pragma unroll
    for (int off = 32; off > 0; off >>= 1) wj = min(wj, __shfl_xor(wj, off));
    if (wj == 0x7fffffff) break;
    if (((wj >> 2) & 63) == lane) tiemask &= ~(1u << (((wj >> 8) << 2) | (wj & 3)));
    if (lane == 0) selj_sh[wave][taken] = wj;
    ++taken;
  }
  int js[KK];
  float es[KK];
#pragma unroll
  for (int k = 0; k < KK; ++k) {
    js[k] = selj_sh[wave][k];
    es[k] = srow[js[k]];   // L2-hot broadcast re-read
  }
  float mx = 0.f;
#pragma unroll
  for (int k = 0; k < KK; ++k) mx = fmaxf(mx, fabsf(es[k]));
  float ssum = 0.f;
#pragma unroll
  for (int k = 0; k < KK; ++k) {
    float ex = expf(fabsf(es[k]) - mx);
    ssum += ex;
    es[k] = sgnf(es[k]) * ex;
  }
  float inv = 1.f / ssum;
  int dbase = lane * 8;
  const float* m0row = mv0 + m * DD + dbase;
  float4 a0 = *reinterpret_cast<const float4*>(m0row);
  float4 a1 = *reinterpret_cast<const float4*>(m0row + 4);
  float acc[8] = {a0.x, a0.y, a0.z, a0.w, a1.x, a1.y, a1.z, a1.w};
  float stacc = 0.f;
#pragma unroll
  for (int k = 0; k < KK; ++k) {
    float e = es[k] * inv;
    const float* tv = token_val + ((size_t)b * SS + js[k]) * DD + dbase;
    float4 u0 = *reinterpret_cast<const float4*>(tv);
    float4 u1 = *reinterpret_cast<const float4*>(tv + 4);
    acc[0] += e * u0.x; acc[1] += e * u0.y; acc[2] += e * u0.z; acc[3] += e * u0.w;
    acc[4] += e * u1.x; acc[5] += e * u1.y; acc[6] += e * u1.z; acc[7] += e * u1.w;
    stacc += e * token_state[(size_t)b * SS + js[k]];
  }
  if (lane == 0) ms_w[row] = ms0[m] + stacc;
  float s1 = 0.f, s2 = 0.f;
#pragma unroll
  for (int c = 0; c < 8; ++c) { s1 += acc[c]; s2 += acc[c] * acc[c]; }
  s1 = wave_sum(s1);
  s2 = wave_sum(s2);
  float mean = s1 * (1.0f / DD);
  float var = s2 * (1.0f / DD) - mean * mean;
  float rs = rsqrtf(var + 1e-5f);
  float4 g0 = *reinterpret_cast<const float4*>(ln_g + dbase);
  float4 g1 = *reinterpret_cast<const float4*>(ln_g + dbase + 4);
  float4 b0v = *reinterpret_cast<const float4*>(ln_b + dbase);
  float4 b1v = *reinterpret_cast<const float4*>(ln_b + dbase + 4);
  float4 o0, o1;
  o0.x = (acc[0] - mean) * rs * g0.x + b0v.x;
  o0.y = (acc[1] - mean) * rs * g0.y + b0v.y;
  o0.z = (acc[2] - mean) * rs * g0.z + b0v.z;
  o0.w = (acc[3] - mean) * rs * g0.w + b0v.w;
  o1.x = (acc[4] - mean) * rs * g1.x + b1v.x;
  o1.y = (acc[5] - mean) * rs * g1.y + b1v.y;
  o1.z = (acc[6] - mean) * rs * g1.z + b1v.z;
  o1.w = (acc[7] - mean) * rs * g1.w + b1v.w;
  float* orow = mv1 + (size_t)row * DD + dbase;
  *reinterpret_cast<float4*>(orow) = o0;
  *reinterpret_cast<float4*>(orow + 4) = o1;
}

// ---------------------------------------------------------------------------
// One WAVE per (b,m): pscores[j] = pt1[row,:]·ps1T[b,:,j] (ms1 folded in);
// ballot-threshold top-16 -> edges -> gather mv1 -> residual -> LN -> out.
// ---------------------------------------------------------------------------
__global__ __launch_bounds__(256, 4) void k_prop(
    const float* __restrict__ pt1, const float* __restrict__ ps1T,
    const float* __restrict__ mv1, const float* __restrict__ ln_g,
    const float* __restrict__ ln_b, float* __restrict__ out) {
  int t = threadIdx.x;
  int wave = t >> 6, lane = t & 63;
  int row = blockIdx.x * 4 + wave;
  int b = row >> 8, m = row & 255;
  __shared__ int selj_sh[4][KK];
  __shared__ float selv_sh[4][KK];
  float ptval = pt1[(size_t)row * RR + lane];
  const float* pB = ps1T + (size_t)b * RR * MM + lane * 4;
  float sc[4] = {0.f, 0.f, 0.f, 0.f};
#pragma unroll 8
  for (int r = 0; r < RR; ++r) {
    float w = __shfl(ptval, r);
    float4 pv = *reinterpret_cast<const float4*>(pB + r * MM);
    sc[0] += w * pv.x; sc[1] += w * pv.y; sc[2] += w * pv.z; sc[3] += w * pv.w;
  }
  int jbase = lane * 4;
  unsigned au[4];
#pragma unroll
  for (int c = 0; c < 4; ++c) au[c] = __float_as_uint(sc[c]) & 0x7fffffffu;
  unsigned lo = 0u, hi = 0x7f800000u, thr = 0u;
  bool early = false;
  while (lo < hi) {
    unsigned mid = lo + ((hi - lo + 1u) >> 1);
    int cnt = 0;
#pragma unroll
    for (int c = 0; c < 4; ++c) cnt += __popcll(__ballot(au[c] >= mid));
    if (cnt == KK) { thr = mid; early = true; break; }
    if (cnt > KK) lo = mid; else hi = mid - 1u;
  }
  if (!early) thr = lo;
  unsigned long long ltmask = (1ull << lane) - 1ull;
  int s = 0;
  unsigned tiemask = 0u;
#pragma unroll
  for (int c = 0; c < 4; ++c) {
    bool sg = early ? (au[c] >= thr) : (au[c] > thr);
    unsigned long long mk = __ballot(sg);
    if (sg) {
      int slot = s + __popcll(mk & ltmask);
      selj_sh[wave][slot] = jbase + c;
      selv_sh[wave][slot] = sc[c];
    }
    s += __popcll(mk);
    if (!early && au[c] == thr) tiemask |= 1u << c;
  }
  int taken = s;
  while (taken < KK) {
    int myj = 0x7fffffff;
#pragma unroll
    for (int c = 0; c < 4; ++c)
      if ((tiemask >> c) & 1u) myj = min(myj, jbase + c);
    int wj = myj;
#pragma unroll
    for (int off = 32; off > 0; off >>= 1) wj = min(wj, __shfl_xor(wj, off));
    if (wj == 0x7fffffff) break;
    if (wj >= jbase && wj < jbase + 4) {
      tiemask &= ~(1u << (wj - jbase));
      selv_sh[wave][taken] = sc[wj - jbase];
      if (lane == (wj >> 2)) selj_sh[wave][taken] = wj;
    }
    ++taken;
  }
  int js[KK];
  float es[KK];
#pragma unroll
  for (int k = 0; k < KK; ++k) { js[k] = selj_sh[wave][k]; es[k] = selv_sh[wave][k]; }
  float mx = 0.f;
#pragma unroll
  for (int k = 0; k < KK; ++k) mx = fmaxf(mx, fabsf(es[k]));
  float ssum = 0.f;
#pragma unroll
  for (int k = 0; k < KK; ++k) {
    float ex = expf(fabsf(es[k]) - mx);
    ssum += ex;
    es[k] = sgnf(es[k]) * ex;
  }
  float inv = 1.f / ssum;
  int dbase = lane * 8;
  const float* mrow = mv1 + (size_t)row * DD + dbase;
  float4 a0 = *reinterpret_cast<const float4*>(mrow);
  float4 a1 = *reinterpret_cast<const float4*>(mrow + 4);
  float acc[8] = {a0.x, a0.y, a0.z, a0.w, a1.x, a1.y, a1.z, a1.w};
#pragma unroll
  for (int k = 0; k < KK; ++k) {
    float e = es[k] * inv;
    const float* pv = mv1 + ((size_t)b * MM + js[k]) * DD + dbase;
    float4 u0 = *reinterpret_cast<const float4*>(pv);
    float4 u1 = *reinterpret_cast<const float4*>(pv + 4);
    acc[0] += e * u0.x; acc[1] += e * u0.y; acc[2] += e * u0.z; acc[3] += e * u0.w;
    acc[4] += e * u1.x; acc[5] += e * u1.y; acc[6] += e * u1.z; acc[7] += e * u1.w;
  }
  float s1 = 0.f, s2 = 0.f;
#pragma unroll
  for (int c = 0; c < 8; ++c) { s1 += acc[c]; s2 += acc[c] * acc[c]; }
  s1 = wave_sum(s1);
  s2 = wave_sum(s2);
  float mean = s1 * (1.0f / DD);
  float var = s2 * (1.0f / DD) - mean * mean;
  float rs = rsqrtf(var + 1e-5f);
  float4 g0 = *reinterpret_cast<const float4*>(ln_g + dbase);
  float4 g1 = *reinterpret_cast<const float4*>(ln_g + dbase + 4);
  float4 b0v = *reinterpret_cast<const float4*>(ln_b + dbase);
  float4 b1v = *reinterpret_cast<const float4*>(ln_b + dbase + 4);
  float4 o0, o1;
  o0.x = (acc[0] - mean) * rs * g0.x + b0v.x;
  o0.y = (acc[1] - mean) * rs * g0.y + b0v.y;
  o0.z = (acc[2] - mean) * rs * g0.z + b0v.z;
  o0.w = (acc[3] - mean) * rs * g0.w + b0v.w;
  o1.x = (acc[4] - mean) * rs * g1.x + b1v.x;
  o1.y = (acc[5] - mean) * rs * g1.y + b1v.y;
  o1.z = (acc[6] - mean) * rs * g1.z + b1v.z;
  o1.w = (acc[7] - mean) * rs * g1.w + b1v.w;
  float* orow = out + (size_t)row * DD + dbase;
  *reinterpret_cast<float4*>(orow) = o0;
  *reinterpret_cast<float4*>(orow + 4) = o1;
}

extern "C" void kernel_launch(void* const* d_in, const int* in_sizes, int n_in,
                              void* d_out, int out_size, void* d_ws,
                              size_t ws_size, hipStream_t stream) {
  const float* token_val = (const float*)d_in[0];
  const float* token_state = (const float*)d_in[1];
  const float* init_state = (const float*)d_in[2];
  const float* init_val = (const float*)d_in[3];
  const float* rUs_w = (const float*)d_in[4];
  const float* rUs_b = (const float*)d_in[5];
  const float* rUt_w = (const float*)d_in[6];
  const float* rUt_b = (const float*)d_in[7];
  const float* r_w = (const float*)d_in[8];
  const float* pUs_w = (const float*)d_in[9];
  const float* pUs_b = (const float*)d_in[10];
  const float* pUt_w = (const float*)d_in[11];
  const float* pUt_b = (const float*)d_in[12];
  const float* p_w = (const float*)d_in[13];
  const float* ln_g = (const float*)d_in[14];
  const float* ln_b = (const float*)d_in[15];
  float* out = (float*)d_out;

  float* ws = (float*)d_ws;
  float* mv0 = ws;    ws += MM * DD;
  float* pt0 = ws;    ws += MM * RR;
  float* ms0 = ws;    ws += MM;
  float* ps = ws;     ws += (size_t)BB * SS * RR;
  float* scores = ws; ws += (size_t)BB * MM * SS;
  float* mv1 = ws;    ws += (size_t)BB * MM * DD;
  float* ms_w = ws;   ws += BB * MM;
  float* ms1 = ws;    ws += BB * MM;
  float* pt1 = ws;    ws += (size_t)BB * MM * RR;
  float* ps1T = ws;   ws += (size_t)BB * RR * MM;

  k_init<<<MM, 256, 0, stream>>>(init_val, init_state, ln_g, ln_b, rUt_w,
                                 rUt_b, r_w, mv0, pt0, ms0);
  k_ps<<<(BB * SS) / 64, 256, 0, stream>>>(token_val, rUs_w, rUs_b, ps);
  dim3 gs(SS / 128, MM / 128, BB);
  k_scores<<<gs, 256, 0, stream>>>(pt0, ps, scores);
  k_write<<<(BB * MM) / 4, 256, 0, stream>>>(scores, token_val, token_state,
                                             mv0, ms0, ln_g, ln_b, mv1, ms_w);
  k_state_softmax<<<BB, 256, 0, stream>>>(ms_w, ms1);
  k_gemm_pair<<<128, 256, 0, stream>>>(mv1, pUt_w, pUt_b, p_w, pUs_w, pUs_b,
                                       ms1, pt1, ps1T);
  k_prop<<<(BB * MM) / 4, 256, 0, stream>>>(pt1, ps1T, mv1, ln_g, ln_b, out);
}

// Round 15
// 148.027 us; speedup vs baseline: 1.1692x; 1.0756x over previous
//
#include <hip/hip_runtime.h>
#include <hip/hip_bf16.h>
#include <math.h>

#define BB 16
#define SS 2048
#define DD 512
#define MM 256
#define RR 64
#define KK 16
#define GPAD 68

__device__ __forceinline__ float wave_sum(float v) {
#pragma unroll
  for (int off = 32; off > 0; off >>= 1) v += __shfl_xor(v, off);
  return v;
}

__device__ __forceinline__ float sgnf(float v) {
  return (v > 0.f) ? 1.f : ((v < 0.f) ? -1.f : 0.f);
}

// ---------------------------------------------------------------------------
// gemm_body (best measured): 64-row tile, micro 4x4, K-chunk 32.
// ---------------------------------------------------------------------------
template <bool TRANS_OUT>
__device__ __forceinline__ void gemm_body(
    const float* __restrict__ A, const float* __restrict__ W,
    const float* __restrict__ bias, const float* __restrict__ colscale,
    float csmul, float* __restrict__ C, int row0, float (*Ast)[GPAD],
    float (*Ws)[GPAD]) {
  int tid = threadIdx.x;
  int ty = tid >> 4, tx = tid & 15;
  float acc[4][4] = {};
  for (int kc = 0; kc < DD; kc += 32) {
#pragma unroll
    for (int i = 0; i < 2; ++i) {
      int s4 = i * 256 + tid;
      int r = s4 >> 3;
      int k4 = s4 & 7;
      float4 v = *reinterpret_cast<const float4*>(
          &A[(size_t)(row0 + r) * DD + kc + k4 * 4]);
      Ast[k4 * 4 + 0][r] = v.x;
      Ast[k4 * 4 + 1][r] = v.y;
      Ast[k4 * 4 + 2][r] = v.z;
      Ast[k4 * 4 + 3][r] = v.w;
    }
#pragma unroll
    for (int i = 0; i < 2; ++i) {
      int s4 = i * 256 + tid;
      int r = s4 >> 4;
      int c4 = s4 & 15;
      float4 v = *reinterpret_cast<const float4*>(
          &W[(size_t)(kc + r) * RR + c4 * 4]);
      *reinterpret_cast<float4*>(&Ws[r][c4 * 4]) = v;
    }
    __syncthreads();
#pragma unroll
    for (int k = 0; k < 32; ++k) {
      float4 a4 = *reinterpret_cast<const float4*>(&Ast[k][ty * 4]);
      float4 w4 = *reinterpret_cast<const float4*>(&Ws[k][tx * 4]);
      acc[0][0] += a4.x * w4.x; acc[0][1] += a4.x * w4.y;
      acc[0][2] += a4.x * w4.z; acc[0][3] += a4.x * w4.w;
      acc[1][0] += a4.y * w4.x; acc[1][1] += a4.y * w4.y;
      acc[1][2] += a4.y * w4.z; acc[1][3] += a4.y * w4.w;
      acc[2][0] += a4.z * w4.x; acc[2][1] += a4.z * w4.y;
      acc[2][2] += a4.z * w4.z; acc[2][3] += a4.z * w4.w;
      acc[3][0] += a4.w * w4.x; acc[3][1] += a4.w * w4.y;
      acc[3][2] += a4.w * w4.z; acc[3][3] += a4.w * w4.w;
    }
    __syncthreads();
  }
#pragma unroll
  for (int i = 0; i < 4; ++i) {
    int rr = row0 + ty * 4 + i;
    if (TRANS_OUT) {
#pragma unroll
      for (int j = 0; j < 4; ++j) {
        int cc = tx * 4 + j;
        float v = acc[i][j] + bias[cc];
        if (colscale) v *= colscale[cc] * csmul;
        C[((size_t)(rr >> 8) * RR + cc) * MM + (rr & 255)] = v;
      }
    } else {
      float4 o;
      o.x = acc[i][0] + bias[tx * 4];
      o.y = acc[i][1] + bias[tx * 4 + 1];
      o.z = acc[i][2] + bias[tx * 4 + 2];
      o.w = acc[i][3] + bias[tx * 4 + 3];
      if (colscale) {
        o.x *= colscale[tx * 4] * csmul; o.y *= colscale[tx * 4 + 1] * csmul;
        o.z *= colscale[tx * 4 + 2] * csmul; o.w *= colscale[tx * 4 + 3] * csmul;
      }
      *reinterpret_cast<float4*>(&C[(size_t)rr * RR + tx * 4]) = o;
    }
  }
}

// ---------------------------------------------------------------------------
// Fused k_ps + k_init: blocks [0,512) do the ps GEMM; blocks [512,768) do
// init (LN(init_val[m]) -> mv0, parallel pt0, block 512 also computes ms0).
// Independent inputs/outputs -> init work hides under the GEMM.
// ---------------------------------------------------------------------------
__global__ __launch_bounds__(256) void k_ps_init(
    const float* __restrict__ token_val, const float* __restrict__ rUs_w,
    const float* __restrict__ rUs_b, float* __restrict__ ps,
    const float* __restrict__ init_val, const float* __restrict__ init_state,
    const float* __restrict__ ln_g, const float* __restrict__ ln_b,
    const float* __restrict__ rUt_w, const float* __restrict__ rUt_b,
    const float* __restrict__ r_w, float* __restrict__ mv0,
    float* __restrict__ pt0, float* __restrict__ ms0) {
  __shared__ float Ast[32][GPAD];
  __shared__ float Ws[32][GPAD];
  int t = threadIdx.x;
  if (blockIdx.x < 512) {
    gemm_body<false>(token_val, rUs_w, rUs_b, nullptr, 1.f, ps,
                     blockIdx.x * 64, Ast, Ws);
    return;
  }
  int m = blockIdx.x - 512;
  float* row = &Ast[0][0];      // reuse LDS: 512 floats
  float* red = &Ws[0][0];       // 8 floats
  float* part = &Ws[1][0];      // 4*64 floats (fits GPAD rows 1..4)
  if (m == 0) {                 // fused ms0 softmax
    float v = init_state[t];
    float a = fabsf(v);
    float mx = a;
#pragma unroll
    for (int off = 32; off > 0; off >>= 1) mx = fmaxf(mx, __shfl_xor(mx, off));
    if ((t & 63) == 0) red[4 + (t >> 6)] = mx;
    __syncthreads();
    mx = fmaxf(fmaxf(red[4], red[5]), fmaxf(red[6], red[7]));
    __syncthreads();
    float e = expf(a - mx);
    float ssum = wave_sum(e);
    if ((t & 63) == 0) red[4 + (t >> 6)] = ssum;
    __syncthreads();
    ssum = red[4] + red[5] + red[6] + red[7];
    ms0[t] = sgnf(v) * e / ssum * 4.0f;
    __syncthreads();
  }
  float x0 = init_val[m * DD + t];
  float x1 = init_val[m * DD + t + 256];
  float s = wave_sum(x0 + x1);
  float sq = wave_sum(x0 * x0 + x1 * x1);
  __syncthreads();
  if ((t & 63) == 0) { red[t >> 6] = s; red[4 + (t >> 6)] = sq; }
  __syncthreads();
  float mean = (red[0] + red[1] + red[2] + red[3]) * (1.0f / DD);
  float var = (red[4] + red[5] + red[6] + red[7]) * (1.0f / DD) - mean * mean;
  float rs = rsqrtf(var + 1e-5f);
  float n0 = (x0 - mean) * rs * ln_g[t] + ln_b[t];
  float n1 = (x1 - mean) * rs * ln_g[t + 256] + ln_b[t + 256];
  mv0[m * DD + t] = n0;
  mv0[m * DD + t + 256] = n1;
  row[t] = n0;
  row[t + 256] = n1;
  __syncthreads();
  // pt0: 4 K-segments x 64 r in parallel (all 256 threads)
  {
    int r = t & 63, q = t >> 6;
    float acc = 0.f;
    const float* wp = rUt_w + (size_t)(q * 128) * RR + r;
#pragma unroll 16
    for (int d = 0; d < 128; ++d) acc += row[q * 128 + d] * wp[d * RR];
    part[q * RR + r] = acc;
  }
  __syncthreads();
  if (t < RR) {
    float acc = part[t] + part[RR + t] + part[2 * RR + t] + part[3 * RR + t] +
                rUt_b[t];
    pt0[m * RR + t] = acc * r_w[t] * 0.1f;
  }
}

__global__ __launch_bounds__(256) void k_gemm_pair(
    const float* __restrict__ mv1, const float* __restrict__ pUt_w,
    const float* __restrict__ pUt_b, const float* __restrict__ p_w,
    const float* __restrict__ pUs_w, const float* __restrict__ pUs_b,
    float* __restrict__ pt1, float* __restrict__ ps1T) {
  __shared__ float Ast[32][GPAD];
  __shared__ float Ws[32][GPAD];
  if (blockIdx.x < 64) {
    gemm_body<false>(mv1, pUt_w, pUt_b, p_w, 0.1f, pt1, blockIdx.x * 64,
                     Ast, Ws);
  } else {
    gemm_body<true>(mv1, pUs_w, pUs_b, nullptr, 1.f, ps1T,
                    (blockIdx.x - 64) * 64, Ast, Ws);
  }
}

// ---------------------------------------------------------------------------
// k_scores: scores[b,m,j] = pt0[m,:]·ps[b,j,:] (K=64).
// Tile 128m x 128j, 256 threads, micro 8m x 8j: per k 4 reads -> 64 FMA.
// ---------------------------------------------------------------------------
#define PSW 144
__device__ __forceinline__ int psw(int j) { return j + ((j >> 5) << 2); }

__global__ __launch_bounds__(256) void k_scores(
    const float* __restrict__ pt0, const float* __restrict__ ps,
    float* __restrict__ scores) {
  __shared__ float PtT[RR][128];  // [k][m] 32KB
  __shared__ float PsT[RR][PSW];  // [k][j skewed] 36KB
  int t = threadIdx.x;
  int b = blockIdx.z;
  int m0 = blockIdx.y * 128;
  int j0 = blockIdx.x * 128;
#pragma unroll
  for (int ii = 0; ii < 2; ++ii) {
    int slot = ii * 256 + t;
    int tm4 = slot >> 4, tk4 = slot & 15;
    const float* base = pt0 + (size_t)(m0 + tm4 * 4) * RR + tk4 * 4;
    float4 v0 = *reinterpret_cast<const float4*>(base);
    float4 v1 = *reinterpret_cast<const float4*>(base + RR);
    float4 v2 = *reinterpret_cast<const float4*>(base + 2 * RR);
    float4 v3 = *reinterpret_cast<const float4*>(base + 3 * RR);
    float4 w;
    w.x = v0.x; w.y = v1.x; w.z = v2.x; w.w = v3.x;
    *reinterpret_cast<float4*>(&PtT[tk4 * 4 + 0][tm4 * 4]) = w;
    w.x = v0.y; w.y = v1.y; w.z = v2.y; w.w = v3.y;
    *reinterpret_cast<float4*>(&PtT[tk4 * 4 + 1][tm4 * 4]) = w;
    w.x = v0.z; w.y = v1.z; w.z = v2.z; w.w = v3.z;
    *reinterpret_cast<float4*>(&PtT[tk4 * 4 + 2][tm4 * 4]) = w;
    w.x = v0.w; w.y = v1.w; w.z = v2.w; w.w = v3.w;
    *reinterpret_cast<float4*>(&PtT[tk4 * 4 + 3][tm4 * 4]) = w;
  }
#pragma unroll
  for (int ii = 0; ii < 2; ++ii) {
    int slot = ii * 256 + t;
    int jt = slot >> 4, kt = slot & 15;
    const float* base = ps + ((size_t)b * SS + j0 + jt * 4) * RR + kt * 4;
    float4 v0 = *reinterpret_cast<const float4*>(base);
    float4 v1 = *reinterpret_cast<const float4*>(base + RR);
    float4 v2 = *reinterpret_cast<const float4*>(base + 2 * RR);
    float4 v3 = *reinterpret_cast<const float4*>(base + 3 * RR);
    int jc = psw(jt * 4);
    float4 w;
    w.x = v0.x; w.y = v1.x; w.z = v2.x; w.w = v3.x;
    *reinterpret_cast<float4*>(&PsT[kt * 4 + 0][jc]) = w;
    w.x = v0.y; w.y = v1.y; w.z = v2.y; w.w = v3.y;
    *reinterpret_cast<float4*>(&PsT[kt * 4 + 1][jc]) = w;
    w.x = v0.z; w.y = v1.z; w.z = v2.z; w.w = v3.z;
    *reinterpret_cast<float4*>(&PsT[kt * 4 + 2][jc]) = w;
    w.x = v0.w; w.y = v1.w; w.z = v2.w; w.w = v3.w;
    *reinterpret_cast<float4*>(&PsT[kt * 4 + 3][jc]) = w;
  }
  __syncthreads();
  int jg = t & 15;
  int mg = t >> 4;
  int jlo = psw(jg * 8);
  float acc[8][8] = {};
#pragma unroll
  for (int k = 0; k < RR; ++k) {
    float4 a0 = *reinterpret_cast<const float4*>(&PtT[k][mg * 8]);
    float4 a1 = *reinterpret_cast<const float4*>(&PtT[k][mg * 8 + 4]);
    float4 w0 = *reinterpret_cast<const float4*>(&PsT[k][jlo]);
    float4 w1 = *reinterpret_cast<const float4*>(&PsT[k][jlo + 4]);
    float av[8] = {a0.x, a0.y, a0.z, a0.w, a1.x, a1.y, a1.z, a1.w};
    float wv[8] = {w0.x, w0.y, w0.z, w0.w, w1.x, w1.y, w1.z, w1.w};
#pragma unroll
    for (int r = 0; r < 8; ++r)
#pragma unroll
      for (int cc = 0; cc < 8; ++cc) acc[r][cc] += av[r] * wv[cc];
  }
  float* obase =
      scores + (size_t)b * MM * SS + (size_t)(m0 + mg * 8) * SS + j0 + jg * 8;
#pragma unroll
  for (int r = 0; r < 8; ++r) {
    float4 o0, o1;
    o0.x = acc[r][0]; o0.y = acc[r][1]; o0.z = acc[r][2]; o0.w = acc[r][3];
    o1.x = acc[r][4]; o1.y = acc[r][5]; o1.z = acc[r][6]; o1.w = acc[r][7];
    *reinterpret_cast<float4*>(obase + (size_t)r * SS) = o0;
    *reinterpret_cast<float4*>(obase + (size_t)r * SS + 4) = o1;
  }
}

// ---------------------------------------------------------------------------
// One WAVE per (b,m) row. Ballot binary-search top-16 from registers;
// selected values re-read from L2-hot scores row. XCD b-affinity swizzle.
// ---------------------------------------------------------------------------
__global__ __launch_bounds__(256) void k_write(
    const float* __restrict__ scores, const float* __restrict__ token_val,
    const float* __restrict__ token_state, const float* __restrict__ mv0,
    const float* __restrict__ ms0, const float* __restrict__ ln_g,
    const float* __restrict__ ln_b, float* __restrict__ mv1,
    float* __restrict__ ms_w) {
  int t = threadIdx.x;
  int wave = t >> 6, lane = t & 63;
  int i = blockIdx.x;
  int slot = i >> 3;
  int b = 2 * (i & 7) + (slot >> 6);
  int m = (slot & 63) * 4 + wave;
  int row = b * MM + m;
  __shared__ int selj_sh[4][KK];
  const float* srow = scores + (size_t)row * SS;
  unsigned au[32];
  unsigned maxa = 0u;
#pragma unroll
  for (int ch = 0; ch < 8; ++ch) {
    float4 q = *reinterpret_cast<const float4*>(srow + (ch * 64 + lane) * 4);
    au[ch * 4 + 0] = __float_as_uint(q.x) & 0x7fffffffu;
    au[ch * 4 + 1] = __float_as_uint(q.y) & 0x7fffffffu;
    au[ch * 4 + 2] = __float_as_uint(q.z) & 0x7fffffffu;
    au[ch * 4 + 3] = __float_as_uint(q.w) & 0x7fffffffu;
    maxa = max(maxa, max(max(au[ch * 4], au[ch * 4 + 1]),
                         max(au[ch * 4 + 2], au[ch * 4 + 3])));
  }
#pragma unroll
  for (int off = 32; off > 0; off >>= 1)
    maxa = max(maxa, (unsigned)__shfl_xor((int)maxa, off));
  unsigned lo = 0u, hi = maxa, thr = 0u;
  bool early = false;
  while (lo < hi) {
    unsigned mid = lo + ((hi - lo + 1u) >> 1);
    int cnt = 0;
#pragma unroll
    for (int c = 0; c < 32; ++c) cnt += __popcll(__ballot(au[c] >= mid));
    if (cnt == KK) { thr = mid; early = true; break; }
    if (cnt > KK) lo = mid; else hi = mid - 1u;
  }
  if (!early) thr = lo;
  unsigned long long ltmask = (1ull << lane) - 1ull;
  int s = 0;
  unsigned tiemask = 0u;
#pragma unroll
  for (int c = 0; c < 32; ++c) {
    bool sg = early ? (au[c] >= thr) : (au[c] > thr);
    unsigned long long mk = __ballot(sg);
    if (sg)
      selj_sh[wave][s + __popcll(mk & ltmask)] =
          (c >> 2) * 256 + lane * 4 + (c & 3);
    s += __popcll(mk);
    if (!early && au[c] == thr) tiemask |= 1u << c;
  }
  int taken = s;
  while (taken < KK) {
    int myj = 0x7fffffff;
#pragma unroll
    for (int c = 0; c < 32; ++c)
      if ((tiemask >> c) & 1u) {
        int j = (c >> 2) * 256 + lane * 4 + (c & 3);
        myj = min(myj, j);
      }
    int wj = myj;
#pragma unroll
    for (int off = 32; off > 0; off >>= 1) wj = min(wj, __shfl_xor(wj, off));
    if (wj == 0x7fffffff) break;
    if (((wj >> 2) & 63) == lane) tiemask &= ~(1u << (((wj >> 8) << 2) | (wj & 3)));
    if (lane == 0) selj_sh[wave][taken] = wj;
    ++taken;
  }
  int js[KK];
  float es[KK];
#pragma unroll
  for (int k = 0; k < KK; ++k) {
    js[k] = selj_sh[wave][k];
    es[k] = srow[js[k]];
  }
  float mx = 0.f;
#pragma unroll
  for (int k = 0; k < KK; ++k) mx = fmaxf(mx, fabsf(es[k]));
  float ssum = 0.f;
#pragma unroll
  for (int k = 0; k < KK; ++k) {
    float ex = expf(fabsf(es[k]) - mx);
    ssum += ex;
    es[k] = sgnf(es[k]) * ex;
  }
  float inv = 1.f / ssum;
  int dbase = lane * 8;
  const float* m0row = mv0 + m * DD + dbase;
  float4 a0 = *reinterpret_cast<const float4*>(m0row);
  float4 a1 = *reinterpret_cast<const float4*>(m0row + 4);
  float acc[8] = {a0.x, a0.y, a0.z, a0.w, a1.x, a1.y, a1.z, a1.w};
  float stacc = 0.f;
#pragma unroll
  for (int k = 0; k < KK; ++k) {
    float e = es[k] * inv;
    const float* tv = token_val + ((size_t)b * SS + js[k]) * DD + dbase;
    float4 u0 = *reinterpret_cast<const float4*>(tv);
    float4 u1 = *reinterpret_cast<const float4*>(tv + 4);
    acc[0] += e * u0.x; acc[1] += e * u0.y; acc[2] += e * u0.z; acc[3] += e * u0.w;
    acc[4] += e * u1.x; acc[5] += e * u1.y; acc[6] += e * u1.z; acc[7] += e * u1.w;
    stacc += e * token_state[(size_t)b * SS + js[k]];
  }
  if (lane == 0) ms_w[row] = ms0[m] + stacc;
  float s1 = 0.f, s2 = 0.f;
#pragma unroll
  for (int c = 0; c < 8; ++c) { s1 += acc[c]; s2 += acc[c] * acc[c]; }
  s1 = wave_sum(s1);
  s2 = wave_sum(s2);
  float mean = s1 * (1.0f / DD);
  float var = s2 * (1.0f / DD) - mean * mean;
  float rs = rsqrtf(var + 1e-5f);
  float4 g0 = *reinterpret_cast<const float4*>(ln_g + dbase);
  float4 g1 = *reinterpret_cast<const float4*>(ln_g + dbase + 4);
  float4 b0v = *reinterpret_cast<const float4*>(ln_b + dbase);
  float4 b1v = *reinterpret_cast<const float4*>(ln_b + dbase + 4);
  float4 o0, o1;
  o0.x = (acc[0] - mean) * rs * g0.x + b0v.x;
  o0.y = (acc[1] - mean) * rs * g0.y + b0v.y;
  o0.z = (acc[2] - mean) * rs * g0.z + b0v.z;
  o0.w = (acc[3] - mean) * rs * g0.w + b0v.w;
  o1.x = (acc[4] - mean) * rs * g1.x + b1v.x;
  o1.y = (acc[5] - mean) * rs * g1.y + b1v.y;
  o1.z = (acc[6] - mean) * rs * g1.z + b1v.z;
  o1.w = (acc[7] - mean) * rs * g1.w + b1v.w;
  float* orow = mv1 + (size_t)row * DD + dbase;
  *reinterpret_cast<float4*>(orow) = o0;
  *reinterpret_cast<float4*>(orow + 4) = o1;
}

// ---------------------------------------------------------------------------
// k_prop with inline ms1 softmax: block prelude computes ms1[b,:] from ms_w
// (4 waves, 256 vals); pscores[j] = (pt1·ps1T)[j] * ms1[j]; top-16; gather.
// ---------------------------------------------------------------------------
__global__ __launch_bounds__(256, 4) void k_prop(
    const float* __restrict__ pt1, const float* __restrict__ ps1T,
    const float* __restrict__ ms_w, const float* __restrict__ mv1,
    const float* __restrict__ ln_g, const float* __restrict__ ln_b,
    float* __restrict__ out) {
  int t = threadIdx.x;
  int wave = t >> 6, lane = t & 63;
  int row = blockIdx.x * 4 + wave;
  int b = row >> 8, m = row & 255;
  __shared__ int selj_sh[4][KK];
  __shared__ float selv_sh[4][KK];
  __shared__ float ms1_sh[MM];
  __shared__ float red[4];
  {  // inline signed_softmax_state(ms_w[b,:]) -> ms1_sh
    float v = ms_w[b * MM + t];
    float a = fabsf(v);
    float mx = a;
#pragma unroll
    for (int off = 32; off > 0; off >>= 1) mx = fmaxf(mx, __shfl_xor(mx, off));
    if ((t & 63) == 0) red[t >> 6] = mx;
    __syncthreads();
    mx = fmaxf(fmaxf(red[0], red[1]), fmaxf(red[2], red[3]));
    __syncthreads();
    float e = expf(a - mx);
    float ssum = wave_sum(e);
    if ((t & 63) == 0) red[t >> 6] = ssum;
    __syncthreads();
    ssum = red[0] + red[1] + red[2] + red[3];
    ms1_sh[t] = sgnf(v) * e / ssum * 4.0f;
  }
  __syncthreads();
  float ptval = pt1[(size_t)row * RR + lane];
  const float* pB = ps1T + (size_t)b * RR * MM + lane * 4;
  float sc[4] = {0.f, 0.f, 0.f, 0.f};
#pragma unroll 8
  for (int r = 0; r < RR; ++r) {
    float w = __shfl(ptval, r);
    float4 pv = *reinterpret_cast<const float4*>(pB + r * MM);
    sc[0] += w * pv.x; sc[1] += w * pv.y; sc[2] += w * pv.z; sc[3] += w * pv.w;
  }
  int jbase = lane * 4;
#pragma unroll
  for (int c = 0; c < 4; ++c) sc[c] *= ms1_sh[jbase + c];
  unsigned au[4];
#pragma unroll
  for (int c = 0; c < 4; ++c) au[c] = __float_as_uint(sc[c]) & 0x7fffffffu;
  unsigned lo = 0u, hi = 0x7f800000u, thr = 0u;
  bool early = false;
  while (lo < hi) {
    unsigned mid = lo + ((hi - lo + 1u) >> 1);
    int cnt = 0;
#pragma unroll
    for (int c = 0; c < 4; ++c) cnt += __popcll(__ballot(au[c] >= mid));
    if (cnt == KK) { thr = mid; early = true; break; }
    if (cnt > KK) lo = mid; else hi = mid - 1u;
  }
  if (!early) thr = lo;
  unsigned long long ltmask = (1ull << lane) - 1ull;
  int s = 0;
  unsigned tiemask = 0u;
#pragma unroll
  for (int c = 0; c < 4; ++c) {
    bool sg = early ? (au[c] >= thr) : (au[c] > thr);
    unsigned long long mk = __ballot(sg);
    if (sg) {
      int slot = s + __popcll(mk & ltmask);
      selj_sh[wave][slot] = jbase + c;
      selv_sh[wave][slot] = sc[c];
    }
    s += __popcll(mk);
    if (!early && au[c] == thr) tiemask |= 1u << c;
  }
  int taken = s;
  while (taken < KK) {
    int myj = 0x7fffffff;
#pragma unroll
    for (int c = 0; c < 4; ++c)
      if ((tiemask >> c) & 1u) myj = min(myj, jbase + c);
    int wj = myj;
#pragma unroll
    for (int off = 32; off > 0; off >>= 1) wj = min(wj, __shfl_xor(wj, off));
    if (wj == 0x7fffffff) break;
    if (wj >= jbase && wj < jbase + 4) {
      tiemask &= ~(1u << (wj - jbase));
      selv_sh[wave][taken] = sc[wj - jbase];
      if (lane == (wj >> 2)) selj_sh[wave][taken] = wj;
    }
    ++taken;
  }
  int js[KK];
  float es[KK];
#pragma unroll
  for (int k = 0; k < KK; ++k) { js[k] = selj_sh[wave][k]; es[k] = selv_sh[wave][k]; }
  float mx = 0.f;
#pragma unroll
  for (int k = 0; k < KK; ++k) mx = fmaxf(mx, fabsf(es[k]));
  float ssum = 0.f;
#pragma unroll
  for (int k = 0; k < KK; ++k) {
    float ex = expf(fabsf(es[k]) - mx);
    ssum += ex;
    es[k] = sgnf(es[k]) * ex;
  }
  float inv = 1.f / ssum;
  int dbase = lane * 8;
  const float* mrow = mv1 + (size_t)row * DD + dbase;
  float4 a0 = *reinterpret_cast<const float4*>(mrow);
  float4 a1 = *reinterpret_cast<const float4*>(mrow + 4);
  float acc[8] = {a0.x, a0.y, a0.z, a0.w, a1.x, a1.y, a1.z, a1.w};
#pragma unroll
  for (int k = 0; k < KK; ++k) {
    float e = es[k] * inv;
    const float* pv = mv1 + ((size_t)b * MM + js[k]) * DD + dbase;
    float4 u0 = *reinterpret_cast<const float4*>(pv);
    float4 u1 = *reinterpret_cast<const float4*>(pv + 4);
    acc[0] += e * u0.x; acc[1] += e * u0.y; acc[2] += e * u0.z; acc[3] += e * u0.w;
    acc[4] += e * u1.x; acc[5] += e * u1.y; acc[6] += e * u1.z; acc[7] += e * u1.w;
  }
  float s1 = 0.f, s2 = 0.f;
#pragma unroll
  for (int c = 0; c < 8; ++c) { s1 += acc[c]; s2 += acc[c] * acc[c]; }
  s1 = wave_sum(s1);
  s2 = wave_sum(s2);
  float mean = s1 * (1.0f / DD);
  float var = s2 * (1.0f / DD) - mean * mean;
  float rs = rsqrtf(var + 1e-5f);
  float4 g0 = *reinterpret_cast<const float4*>(ln_g + dbase);
  float4 g1 = *reinterpret_cast<const float4*>(ln_g + dbase + 4);
  float4 b0v = *reinterpret_cast<const float4*>(ln_b + dbase);
  float4 b1v = *reinterpret_cast<const float4*>(ln_b + dbase + 4);
  float4 o0, o1;
  o0.x = (acc[0] - mean) * rs * g0.x + b0v.x;
  o0.y = (acc[1] - mean) * rs * g0.y + b0v.y;
  o0.z = (acc[2] - mean) * rs * g0.z + b0v.z;
  o0.w = (acc[3] - mean) * rs * g0.w + b0v.w;
  o1.x = (acc[4] - mean) * rs * g1.x + b1v.x;
  o1.y = (acc[5] - mean) * rs * g1.y + b1v.y;
  o1.z = (acc[6] - mean) * rs * g1.z + b1v.z;
  o1.w = (acc[7] - mean) * rs * g1.w + b1v.w;
  float* orow = out + (size_t)row * DD + dbase;
  *reinterpret_cast<float4*>(orow) = o0;
  *reinterpret_cast<float4*>(orow + 4) = o1;
}

extern "C" void kernel_launch(void* const* d_in, const int* in_sizes, int n_in,
                              void* d_out, int out_size, void* d_ws,
                              size_t ws_size, hipStream_t stream) {
  const float* token_val = (const float*)d_in[0];
  const float* token_state = (const float*)d_in[1];
  const float* init_state = (const float*)d_in[2];
  const float* init_val = (const float*)d_in[3];
  const float* rUs_w = (const float*)d_in[4];
  const float* rUs_b = (const float*)d_in[5];
  const float* rUt_w = (const float*)d_in[6];
  const float* rUt_b = (const float*)d_in[7];
  const float* r_w = (const float*)d_in[8];
  const float* pUs_w = (const float*)d_in[9];
  const float* pUs_b = (const float*)d_in[10];
  const float* pUt_w = (const float*)d_in[11];
  const float* pUt_b = (const float*)d_in[12];
  const float* p_w = (const float*)d_in[13];
  const float* ln_g = (const float*)d_in[14];
  const float* ln_b = (const float*)d_in[15];
  float* out = (float*)d_out;

  float* ws = (float*)d_ws;
  float* mv0 = ws;    ws += MM * DD;
  float* pt0 = ws;    ws += MM * RR;
  float* ms0 = ws;    ws += MM;
  float* ps = ws;     ws += (size_t)BB * SS * RR;
  float* scores = ws; ws += (size_t)BB * MM * SS;
  float* mv1 = ws;    ws += (size_t)BB * MM * DD;
  float* ms_w = ws;   ws += BB * MM;
  float* pt1 = ws;    ws += (size_t)BB * MM * RR;
  float* ps1T = ws;   ws += (size_t)BB * RR * MM;

  k_ps_init<<<768, 256, 0, stream>>>(token_val, rUs_w, rUs_b, ps, init_val,
                                     init_state, ln_g, ln_b, rUt_w, rUt_b,
                                     r_w, mv0, pt0, ms0);
  dim3 gs(SS / 128, MM / 128, BB);
  k_scores<<<gs, 256, 0, stream>>>(pt0, ps, scores);
  k_write<<<(BB * MM) / 4, 256, 0, stream>>>(scores, token_val, token_state,
                                             mv0, ms0, ln_g, ln_b, mv1, ms_w);
  k_gemm_pair<<<128, 256, 0, stream>>>(mv1, pUt_w, pUt_b, p_w, pUs_w, pUs_b,
                                       pt1, ps1T);
  k_prop<<<(BB * MM) / 4, 256, 0, stream>>>(pt1, ps1T, ms_w, mv1, ln_g, ln_b,
                                            out);
}